// Round 1
// baseline (234.397 us; speedup 1.0000x reference)
//
#include <hip/hip_runtime.h>
#include <math.h>

#define NQ 8
#define NSTATES 256
#define BB 32
#define NH 16
#define TT 1024
#define HD 64
#define HH 1024   // NH*HD

// ---------------------------------------------------------------------------
// Kernel 1: summary[b, nh*64+hd] = mean_t q[b,nh,t,hd]
// One block per (b,nh). 256 threads = 16 float4-cols x 16 t-groups.
// ---------------------------------------------------------------------------
__global__ __launch_bounds__(256) void k_summary(const float4* __restrict__ q4,
                                                 float* __restrict__ summary) {
    const int bid = blockIdx.x;            // b*16 + nh, 0..511
    const int t   = threadIdx.x;
    const int hd4 = t & 15;                // 16 float4 cover HD=64
    const int tg  = t >> 4;                // 16 t-groups
    const float4* base = q4 + (size_t)bid * (TT * (HD / 4));

    float4 acc = make_float4(0.f, 0.f, 0.f, 0.f);
    for (int tt = tg; tt < TT; tt += 16) {
        float4 v = base[tt * (HD / 4) + hd4];
        acc.x += v.x; acc.y += v.y; acc.z += v.z; acc.w += v.w;
    }

    __shared__ float4 red[256];
    red[t] = acc;
    __syncthreads();
    for (int s = 8; s > 0; s >>= 1) {
        if (tg < s) {
            float4 o = red[t + s * 16];
            red[t].x += o.x; red[t].y += o.y; red[t].z += o.z; red[t].w += o.w;
        }
        __syncthreads();
    }
    if (tg == 0) {
        float4 r = red[t];
        float* out = summary + bid * HD + hd4 * 4;   // bid*64 == b*1024 + nh*64
        const float inv = 1.0f / (float)TT;
        out[0] = r.x * inv; out[1] = r.y * inv; out[2] = r.z * inv; out[3] = r.w * inv;
    }
}

// ---------------------------------------------------------------------------
// Kernel 2: per batch — angles -> 8-qubit circuit -> Z expvals -> head scales
// One block per batch, 256 threads == 256 amplitudes in LDS.
// Wire w corresponds to bit (7-w) of the flat state index.
// ---------------------------------------------------------------------------
__global__ __launch_bounds__(256) void k_circuit(
        const float* __restrict__ summary, const float* __restrict__ W_angles,
        const float* __restrict__ b_angles, const float* __restrict__ q_weights,
        const float* __restrict__ W_post, const float* __restrict__ b_post,
        float* __restrict__ scales) {
    const int b = blockIdx.x;
    const int t = threadIdx.x;

    __shared__ float  ang[NQ];
    __shared__ float2 st[NSTATES];
    __shared__ float  zred[4][NQ];
    __shared__ float  qfeat[NQ];

    // ---- angles[i] = dot(summary[b,:], W_angles[i,:]) + b_angles[i] ----
    {
        const int i = t >> 5;          // 8 qubits x 32 lanes
        const int j = t & 31;
        const float* srow = summary + b * HH;
        const float* wrow = W_angles + i * HH;
        float p = 0.f;
        for (int h = j; h < HH; h += 32) p += srow[h] * wrow[h];
        // reduce across the 32-lane group (offsets < 32 stay in-group)
        for (int off = 16; off; off >>= 1) p += __shfl_xor(p, off);
        if (j == 0) ang[i] = p + b_angles[i];
    }

    // ---- init |00..0> ----
    st[t] = make_float2(t == 0 ? 1.f : 0.f, 0.f);
    __syncthreads();

    // 1-qubit gate: D = M * [a0; a1] on wire's bit
    auto gate1q = [&](int wire, float2 M00, float2 M01, float2 M10, float2 M11) {
        const int m = 1 << (7 - wire);
        float2 a0 = st[t & ~m];
        float2 a1 = st[t |  m];
        __syncthreads();
        float2 r;
        if (t & m) {
            r.x = M10.x * a0.x - M10.y * a0.y + M11.x * a1.x - M11.y * a1.y;
            r.y = M10.x * a0.y + M10.y * a0.x + M11.x * a1.y + M11.y * a1.x;
        } else {
            r.x = M00.x * a0.x - M00.y * a0.y + M01.x * a1.x - M01.y * a1.y;
            r.y = M00.x * a0.y + M00.y * a0.x + M01.x * a1.y + M01.y * a1.x;
        }
        st[t] = r;
        __syncthreads();
    };

    auto cnot = [&](int cw, int tw) {
        const int cm = 1 << (7 - cw);
        const int tm = 1 << (7 - tw);
        float2 a = st[(t & cm) ? (t ^ tm) : t];
        __syncthreads();
        st[t] = a;
        __syncthreads();
    };

    // ---- AngleEmbedding: RY(ang[i]) on wire i ----
    for (int i = 0; i < NQ; ++i) {
        const float half = 0.5f * ang[i];
        const float c = cosf(half), s = sinf(half);
        gate1q(i, make_float2(c, 0.f), make_float2(-s, 0.f),
                  make_float2(s, 0.f), make_float2(c, 0.f));
    }

    // ---- StronglyEntanglingLayers ----
    for (int l = 0; l < 2; ++l) {
        for (int i = 0; i < NQ; ++i) {
            const float phi = q_weights[(l * NQ + i) * 3 + 0];
            const float th  = q_weights[(l * NQ + i) * 3 + 1];
            const float om  = q_weights[(l * NQ + i) * 3 + 2];
            const float c = cosf(0.5f * th), s = sinf(0.5f * th);
            const float apo = -0.5f * (phi + om);   // arg of M00
            const float amo =  0.5f * (phi - om);   // arg of -M01/s
            // Rot = RZ(om) RY(th) RZ(phi)
            float2 M00 = make_float2( c * cosf(apo),  c * sinf(apo));   // c e^{-i(phi+om)/2}
            float2 M11 = make_float2( c * cosf(apo), -c * sinf(apo));   // c e^{+i(phi+om)/2}
            float2 M01 = make_float2(-s * cosf(amo), -s * sinf(amo));   // -s e^{+i(phi-om)/2}
            float2 M10 = make_float2( s * cosf(amo), -s * sinf(amo));   //  s e^{-i(phi-om)/2}
            gate1q(i, M00, M01, M10, M11);
        }
        const int r = (l % (NQ - 1)) + 1;
        for (int i = 0; i < NQ; ++i) cnot(i, (i + r) % NQ);
    }

    // ---- expvals <Z_i> ----
    {
        float2 a = st[t];
        float p = a.x * a.x + a.y * a.y;
        float z[NQ];
        for (int i = 0; i < NQ; ++i)
            z[i] = ((t >> (7 - i)) & 1) ? -p : p;
        for (int off = 32; off; off >>= 1)
            for (int i = 0; i < NQ; ++i) z[i] += __shfl_xor(z[i], off);
        const int wid = t >> 6, lane = t & 63;
        if (lane == 0)
            for (int i = 0; i < NQ; ++i) zred[wid][i] = z[i];
        __syncthreads();
        if (t < NQ) qfeat[t] = zred[0][t] + zred[1][t] + zred[2][t] + zred[3][t];
        __syncthreads();
    }

    // ---- head logits -> scales ----
    if (t < NH) {
        float lg = b_post[t];
        for (int i = 0; i < NQ; ++i) lg += qfeat[i] * W_post[t * NQ + i];
        scales[b * NH + t] = 1.0f + 0.5f * tanhf(lg);
    }
}

// ---------------------------------------------------------------------------
// Kernel 3: out = concat(q*sb, k*sb, v*sb), sb per (b, head)
// ---------------------------------------------------------------------------
__global__ __launch_bounds__(256) void k_scale(
        const float4* __restrict__ q4, const float4* __restrict__ k4,
        const float4* __restrict__ v4, const float* __restrict__ scales,
        float4* __restrict__ out4) {
    const int perTensor = BB * NH * TT * HD / 4;   // 8388608 float4
    const int perHead   = TT * HD / 4;             // 16384 float4
    const int total     = 3 * perTensor;
    for (int g = blockIdx.x * blockDim.x + threadIdx.x; g < total;
         g += gridDim.x * blockDim.x) {
        const int tens = g / perTensor;
        const int rem  = g - tens * perTensor;
        const float s  = scales[rem / perHead];
        const float4* in = (tens == 0) ? q4 : (tens == 1) ? k4 : v4;
        float4 x = in[rem];
        x.x *= s; x.y *= s; x.z *= s; x.w *= s;
        out4[g] = x;
    }
}

extern "C" void kernel_launch(void* const* d_in, const int* in_sizes, int n_in,
                              void* d_out, int out_size, void* d_ws, size_t ws_size,
                              hipStream_t stream) {
    const float* q        = (const float*)d_in[0];
    const float* k        = (const float*)d_in[1];
    const float* v        = (const float*)d_in[2];
    const float* W_angles = (const float*)d_in[3];
    const float* b_ang    = (const float*)d_in[4];
    const float* q_w      = (const float*)d_in[5];
    const float* W_post   = (const float*)d_in[6];
    const float* b_post   = (const float*)d_in[7];
    float* out = (float*)d_out;

    float* summary = (float*)d_ws;            // 32*1024 floats = 128 KiB
    float* scales  = summary + BB * HH;       // 512 floats

    k_summary<<<BB * NH, 256, 0, stream>>>((const float4*)q, summary);
    k_circuit<<<BB, 256, 0, stream>>>(summary, W_angles, b_ang, q_w,
                                      W_post, b_post, scales);
    k_scale<<<2048, 256, 0, stream>>>((const float4*)q, (const float4*)k,
                                      (const float4*)v, scales, (float4*)out);
}

// Round 3
// 187.747 us; speedup vs baseline: 1.2485x; 1.2485x over previous
//
#include <hip/hip_runtime.h>
#include <math.h>

#define NQ 8
#define NSTATES 256
#define BB 32
#define NH 16
#define TT 1024
#define HD 64
#define HH 1024   // NH*HD
#define NCHUNK 8  // T-chunks per (b,head) in summary pass

typedef float f32x4 __attribute__((ext_vector_type(4)));

// ---------------------------------------------------------------------------
// Kernel 1: partial sums of q over T.
// grid = 512*NCHUNK blocks; block (bid,chunk) reduces 128 t-rows of head bid.
// part[blk][64] holds the 64-dim partial sum (un-normalized).
// ---------------------------------------------------------------------------
__global__ __launch_bounds__(256) void k_summary(const f32x4* __restrict__ q4,
                                                 float* __restrict__ part) {
    const int blk   = blockIdx.x;        // bid*NCHUNK + chunk
    const int bid   = blk >> 3;
    const int chunk = blk & 7;
    const int t     = threadIdx.x;
    const int hd4   = t & 15;            // 16 f32x4 cover HD=64
    const int tg    = t >> 4;            // 16 t-groups
    const f32x4* base = q4 + (size_t)bid * (TT * (HD / 4))
                           + (size_t)chunk * 128 * (HD / 4);

    f32x4 acc = (f32x4)(0.f);
#pragma unroll
    for (int i = 0; i < 8; ++i) {        // 128 t-rows / 16 groups
        acc += base[(tg + 16 * i) * (HD / 4) + hd4];
    }

    __shared__ f32x4 red[256];
    red[t] = acc;
    __syncthreads();
    for (int s = 8; s > 0; s >>= 1) {
        if (tg < s) red[t] += red[t + s * 16];
        __syncthreads();
    }
    if (tg == 0) {
        f32x4 r = red[t];
        float* out = part + (size_t)blk * HD + hd4 * 4;
        out[0] = r.x; out[1] = r.y; out[2] = r.z; out[3] = r.w;
    }
}

// ---------------------------------------------------------------------------
// Kernel 2: per batch — combine partials -> angles -> 8-qubit circuit ->
// Z expvals -> head scales. One block per batch, 256 threads = 256 amplitudes.
// Wire w corresponds to bit (7-w) of the flat state index.
// ---------------------------------------------------------------------------
__global__ __launch_bounds__(256) void k_circuit(
        const float* __restrict__ part, const float* __restrict__ W_angles,
        const float* __restrict__ b_angles, const float* __restrict__ q_weights,
        const float* __restrict__ W_post, const float* __restrict__ b_post,
        float* __restrict__ scales) {
    const int b = blockIdx.x;
    const int t = threadIdx.x;

    __shared__ float  ssum[HH];
    __shared__ float  ang[NQ];
    __shared__ float2 st[NSTATES];
    __shared__ float  zred[4][NQ];
    __shared__ float  qfeat[NQ];

    // ---- combine NCHUNK partials into summary (mean over T) ----
    for (int h = t; h < HH; h += 256) {
        const int nh = h >> 6, hd = h & 63;
        const float* p = part + ((size_t)(b * NH + nh) * NCHUNK) * HD + hd;
        float s = 0.f;
#pragma unroll
        for (int c = 0; c < NCHUNK; ++c) s += p[c * HD];
        ssum[h] = s * (1.0f / (float)TT);
    }
    __syncthreads();

    // ---- angles[i] = dot(summary[b,:], W_angles[i,:]) + b_angles[i] ----
    {
        const int i = t >> 5;          // 8 qubits x 32 lanes
        const int j = t & 31;
        const float* wrow = W_angles + i * HH;
        float p = 0.f;
        for (int h = j; h < HH; h += 32) p += ssum[h] * wrow[h];
        for (int off = 16; off; off >>= 1) p += __shfl_xor(p, off);
        if (j == 0) ang[i] = p + b_angles[i];
    }

    // ---- init |00..0> ----
    st[t] = make_float2(t == 0 ? 1.f : 0.f, 0.f);
    __syncthreads();

    auto gate1q = [&](int wire, float2 M00, float2 M01, float2 M10, float2 M11) {
        const int m = 1 << (7 - wire);
        float2 a0 = st[t & ~m];
        float2 a1 = st[t |  m];
        __syncthreads();
        float2 r;
        if (t & m) {
            r.x = M10.x * a0.x - M10.y * a0.y + M11.x * a1.x - M11.y * a1.y;
            r.y = M10.x * a0.y + M10.y * a0.x + M11.x * a1.y + M11.y * a1.x;
        } else {
            r.x = M00.x * a0.x - M00.y * a0.y + M01.x * a1.x - M01.y * a1.y;
            r.y = M00.x * a0.y + M00.y * a0.x + M01.x * a1.y + M01.y * a1.x;
        }
        st[t] = r;
        __syncthreads();
    };

    auto cnot = [&](int cw, int tw) {
        const int cm = 1 << (7 - cw);
        const int tm = 1 << (7 - tw);
        float2 a = st[(t & cm) ? (t ^ tm) : t];
        __syncthreads();
        st[t] = a;
        __syncthreads();
    };

    // ---- AngleEmbedding: RY(ang[i]) on wire i ----
    for (int i = 0; i < NQ; ++i) {
        const float half = 0.5f * ang[i];
        const float c = cosf(half), s = sinf(half);
        gate1q(i, make_float2(c, 0.f), make_float2(-s, 0.f),
                  make_float2(s, 0.f), make_float2(c, 0.f));
    }

    // ---- StronglyEntanglingLayers ----
    for (int l = 0; l < 2; ++l) {
        for (int i = 0; i < NQ; ++i) {
            const float phi = q_weights[(l * NQ + i) * 3 + 0];
            const float th  = q_weights[(l * NQ + i) * 3 + 1];
            const float om  = q_weights[(l * NQ + i) * 3 + 2];
            const float c = cosf(0.5f * th), s = sinf(0.5f * th);
            const float apo = -0.5f * (phi + om);
            const float amo =  0.5f * (phi - om);
            // Rot = RZ(om) RY(th) RZ(phi)
            float2 M00 = make_float2( c * cosf(apo),  c * sinf(apo));
            float2 M11 = make_float2( c * cosf(apo), -c * sinf(apo));
            float2 M01 = make_float2(-s * cosf(amo), -s * sinf(amo));
            float2 M10 = make_float2( s * cosf(amo), -s * sinf(amo));
            gate1q(i, M00, M01, M10, M11);
        }
        const int r = (l % (NQ - 1)) + 1;
        for (int i = 0; i < NQ; ++i) cnot(i, (i + r) % NQ);
    }

    // ---- expvals <Z_i> ----
    {
        float2 a = st[t];
        float p = a.x * a.x + a.y * a.y;
        float z[NQ];
        for (int i = 0; i < NQ; ++i)
            z[i] = ((t >> (7 - i)) & 1) ? -p : p;
        for (int off = 32; off; off >>= 1)
            for (int i = 0; i < NQ; ++i) z[i] += __shfl_xor(z[i], off);
        const int wid = t >> 6, lane = t & 63;
        if (lane == 0)
            for (int i = 0; i < NQ; ++i) zred[wid][i] = z[i];
        __syncthreads();
        if (t < NQ) qfeat[t] = zred[0][t] + zred[1][t] + zred[2][t] + zred[3][t];
        __syncthreads();
    }

    // ---- head logits -> scales ----
    if (t < NH) {
        float lg = b_post[t];
        for (int i = 0; i < NQ; ++i) lg += qfeat[i] * W_post[t * NQ + i];
        scales[b * NH + t] = 1.0f + 0.5f * tanhf(lg);
    }
}

// ---------------------------------------------------------------------------
// Kernel 3: out = concat(q*sb, k*sb, v*sb).
// grid = (8192, 3): y selects tensor (scalar), x selects 1024-float4 block.
// 16 blocks per (b,head) -> scale is block-uniform. No per-thread divisions.
// q (y==0) dispatches first and uses cached loads (L3-hot from k_summary);
// k/v use non-temporal loads, all stores non-temporal (no reuse).
// ---------------------------------------------------------------------------
__global__ __launch_bounds__(256) void k_scale(
        const f32x4* __restrict__ q4, const f32x4* __restrict__ k4,
        const f32x4* __restrict__ v4, const float* __restrict__ scales,
        f32x4* __restrict__ out4) {
    const int  perTensor = BB * NH * TT * HD / 4;   // 8388608 f32x4
    const int  tens = blockIdx.y;
    const int  blk  = blockIdx.x;                   // 0..8191
    const int  t    = threadIdx.x;
    const float s   = scales[blk >> 4];             // 16 blocks per head

    const f32x4* in = (tens == 0) ? q4 : (tens == 1) ? k4 : v4;
    const size_t base = (size_t)blk * 1024;
    const f32x4* inp  = in + base;
    f32x4*       outp = out4 + (size_t)tens * perTensor + base;

#pragma unroll
    for (int i = 0; i < 4; ++i) {
        const int idx = i * 256 + t;
        f32x4 x = (tens == 0) ? inp[idx]
                              : __builtin_nontemporal_load(&inp[idx]);
        x *= s;
        __builtin_nontemporal_store(x, &outp[idx]);
    }
}

extern "C" void kernel_launch(void* const* d_in, const int* in_sizes, int n_in,
                              void* d_out, int out_size, void* d_ws, size_t ws_size,
                              hipStream_t stream) {
    const float* q        = (const float*)d_in[0];
    const float* k        = (const float*)d_in[1];
    const float* v        = (const float*)d_in[2];
    const float* W_angles = (const float*)d_in[3];
    const float* b_ang    = (const float*)d_in[4];
    const float* q_w      = (const float*)d_in[5];
    const float* W_post   = (const float*)d_in[6];
    const float* b_post   = (const float*)d_in[7];
    float* out = (float*)d_out;

    float* part   = (float*)d_ws;                       // 4096*64 floats = 1 MiB
    float* scales = part + (size_t)BB * NH * NCHUNK * HD;  // 512 floats

    k_summary<<<BB * NH * NCHUNK, 256, 0, stream>>>((const f32x4*)q, part);
    k_circuit<<<BB, 256, 0, stream>>>(part, W_angles, b_ang, q_w,
                                      W_post, b_post, scales);
    dim3 grid(8192, 3);
    k_scale<<<grid, 256, 0, stream>>>((const f32x4*)q, (const f32x4*)k,
                                      (const f32x4*)v, scales, (f32x4*)out);
}